// Round 5
// baseline (125.218 us; speedup 1.0000x reference)
//
#include <hip/hip_runtime.h>
#include <hip/hip_bf16.h>
#include <cstdint>

#define IN_F   1024
#define OUT_F  1024
#define KTOT   (IN_F + IN_F * 8)      // 9216
#define BATCH  4096

#define BM 128
#define BN 128
#define BK 64
#define NT (KTOT / BK)                // 144 K-steps
#define ROWB (BK * 2)                 // 128 bytes per LDS row
#define SLOT_B 32768                  // bytes per ring slot (A 16K | B 16K)

typedef __attribute__((ext_vector_type(8))) __bf16 bf16x8;
typedef __attribute__((ext_vector_type(4))) float  f32x4;
typedef __attribute__((ext_vector_type(8))) short  short8v;

typedef __attribute__((address_space(1))) const uint32_t gu32;
typedef __attribute__((address_space(3))) uint32_t       lu32;

__device__ __forceinline__ void gl_lds16(const void* g, void* l) {
    __builtin_amdgcn_global_load_lds((gu32*)g, (lu32*)l, 16, 0, 0);
}

// float -> bf16 RNE
__device__ __forceinline__ unsigned short f2bf(float f) {
    unsigned int u = __builtin_bit_cast(unsigned int, f);
    return (unsigned short)((u + 0x7fffu + ((u >> 16) & 1u)) >> 16);
}

// ---------------------------------------------------------------------------
// Build W (OUT_F x KTOT) bf16 row-major: [base_w | spline_w * scaler]
// ---------------------------------------------------------------------------
__global__ void build_w_kernel(const float* __restrict__ base_w,
                               const float* __restrict__ spline_w,
                               const float* __restrict__ scaler,
                               unsigned short* __restrict__ Wb) {
    int idx = blockIdx.x * 256 + threadIdx.x;
    int o = idx >> 10;
    int j = idx & 1023;

    Wb[(size_t)o * KTOT + j] = f2bf(base_w[idx]);

    float s = scaler[idx];
    const float4* sw4 = (const float4*)(spline_w + (size_t)idx * 8);
    float4 w0 = sw4[0], w1 = sw4[1];

    short8v v;
    v[0] = (short)f2bf(w0.x * s); v[1] = (short)f2bf(w0.y * s);
    v[2] = (short)f2bf(w0.z * s); v[3] = (short)f2bf(w0.w * s);
    v[4] = (short)f2bf(w1.x * s); v[5] = (short)f2bf(w1.y * s);
    v[6] = (short)f2bf(w1.z * s); v[7] = (short)f2bf(w1.w * s);
    *(short8v*)(Wb + (size_t)o * KTOT + IN_F + (size_t)j * 8) = v;
}

// ---------------------------------------------------------------------------
// Build A (BATCH x KTOT) bf16: [silu(x) | basis(x)]
// Uniform grid: knot t(i) = 0.4*i - 2.2; constant reciprocal denominators.
// ---------------------------------------------------------------------------
__device__ __forceinline__ float knot(int i) { return 0.4f * (float)i - 2.2f; }

__global__ void build_act_kernel(const float* __restrict__ x,
                                 unsigned short* __restrict__ Act) {
    int idx = blockIdx.x * 256 + threadIdx.x;
    int b = idx >> 10;
    int j = idx & 1023;

    float xv = x[idx];

    float sil = xv * __frcp_rn(1.0f + __expf(-xv));
    Act[(size_t)b * KTOT + j] = f2bf(sil);

    const float r1 = 1.0f / (0.4f + 1e-8f);
    const float r2 = 1.0f / (0.8f + 1e-8f);
    const float r3 = 1.0f / (1.2f + 1e-8f);

    float bas[11];
    #pragma unroll
    for (int i = 0; i < 11; ++i)
        bas[i] = (xv >= knot(i) && xv < knot(i + 1)) ? 1.0f : 0.0f;
    #pragma unroll
    for (int i = 0; i < 10; ++i)
        bas[i] = (xv - knot(i)) * r1 * bas[i] + (knot(i + 2) - xv) * r1 * bas[i + 1];
    #pragma unroll
    for (int i = 0; i < 9; ++i)
        bas[i] = (xv - knot(i)) * r2 * bas[i] + (knot(i + 3) - xv) * r2 * bas[i + 1];
    #pragma unroll
    for (int i = 0; i < 8; ++i)
        bas[i] = (xv - knot(i)) * r3 * bas[i] + (knot(i + 4) - xv) * r3 * bas[i + 1];

    short8v v;
    #pragma unroll
    for (int c = 0; c < 8; ++c) v[c] = (short)f2bf(bas[c]);
    *(short8v*)(Act + (size_t)b * KTOT + IN_F + (size_t)j * 8) = v;
}

// ---------------------------------------------------------------------------
// GEMM: C (4096x1024) f32 = Act . Wb^T.  128x128 tile, BK=64.
// 8 waves = 2(M) x 2(N) x 2(K-parity), 64x64 output tile per wave; wave pairs
// (kp=0/1) sum partials via LDS at the end.
// NEW (r5): register fragment double-buffer — at iter kt, ds_read tile kt+1's
// fragments into buf[NB] while MFMAs consume buf[CB] (loaded last iter, no
// lgkm dependency) -> LDS pipe and MFMA pipe run concurrently instead of
// serializing per barrier epoch (r3/r4 stall: read-burst then compute-burst).
// Staging depth 3 on ring-4, steady vmcnt(8). lgkmcnt(0) drained before each
// barrier => slot (kt-1)&3 has no in-flight readers when restaged at iter kt.
// ---------------------------------------------------------------------------
__global__ __launch_bounds__(512)
void gemm_kernel(const unsigned short* __restrict__ Act,
                 const unsigned short* __restrict__ Wb,
                 float* __restrict__ C) {
    __shared__ char Sm[4 * SLOT_B];    // 128 KB ring; reused for reduction

    const int tid  = threadIdx.x;
    const int lane = tid & 63;
    const int wave = tid >> 6;        // 0..7
    const int kp   = wave >> 2;       // K-parity 0/1
    const int wr   = (wave >> 1) & 1; // M half
    const int wn   = wave & 1;        // N half

    const int bid  = blockIdx.x;
    const int nblk = bid & 7;         // XCD-locked N column
    const int mblk = bid >> 3;
    const int m0 = mblk * BM;
    const int n0 = nblk * BN;

    const int frow = lane & 15;
    const int kgrp = lane >> 4;       // 0..3

    f32x4 acc[4][4] = {};             // 64 VGPRs: 64x64 per wave

    // staging map: thread t covers 16 B at tile byte offset o (shot0) / o+8192
    const int o    = tid * 16;                 // 0..8191
    const int row0 = o >> 7;                   // 0..63
    const int colb = o & 127;
    const int scol = colb ^ ((row0 & 7) << 4); // pre-swizzled source column

    const char* aS0 = (const char*)Act + (size_t)(m0 + row0) * (KTOT * 2) + scol;
    const char* aS1 = aS0 + (size_t)64 * (KTOT * 2);
    const char* bS0 = (const char*)Wb  + (size_t)(n0 + row0) * (KTOT * 2) + scol;
    const char* bS1 = bS0 + (size_t)64 * (KTOT * 2);

    #define STAGE(kt, sl) do {                                       \
        const size_t kk = (size_t)(kt) * ROWB;                       \
        char* d = Sm + (size_t)(sl) * SLOT_B + o;                    \
        gl_lds16(aS0 + kk, d);                                       \
        gl_lds16(aS1 + kk, d + 8192);                                \
        gl_lds16(bS0 + kk, d + 16384);                               \
        gl_lds16(bS1 + kk, d + 24576);                               \
    } while (0)

    const int swz = (lane & 7) << 4;           // fragment row&7 == lane&7
    const int kb  = kp * 64 + kgrp * 16;       // this wave's K=32 half-slice

    bf16x8 aR[2][4], bR[2][4];                 // fragment double-buffer

    #define READFRAGS(sl, AB, BB) do {                                       \
        const char* base_ = Sm + (size_t)(sl) * SLOT_B;                      \
        _Pragma("unroll")                                                    \
        for (int m = 0; m < 4; ++m) {                                        \
            const int r = wr * 64 + m * 16 + frow;                           \
            (AB)[m] = *(const bf16x8*)(base_ + r * ROWB + (kb ^ swz));       \
        }                                                                    \
        _Pragma("unroll")                                                    \
        for (int n = 0; n < 4; ++n) {                                        \
            const int r = wn * 64 + n * 16 + frow;                           \
            (BB)[n] = *(const bf16x8*)(base_ + 16384 + r * ROWB + (kb ^ swz)); \
        }                                                                    \
    } while (0)

    #define MFMA16(AB, BB) do {                                              \
        __builtin_amdgcn_s_setprio(1);                                       \
        _Pragma("unroll")                                                    \
        for (int m = 0; m < 4; ++m)                                          \
            _Pragma("unroll")                                                \
            for (int n = 0; n < 4; ++n)                                      \
                acc[m][n] = __builtin_amdgcn_mfma_f32_16x16x32_bf16(         \
                                (AB)[m], (BB)[n], acc[m][n], 0, 0, 0);       \
        __builtin_amdgcn_s_setprio(0);                                       \
    } while (0)

    // ---- prologue: stage 3 tiles, land tile 0, preload its fragments ------
    STAGE(0, 0);
    STAGE(1, 1);
    STAGE(2, 2);
    asm volatile("s_waitcnt vmcnt(8)" ::: "memory");   // tile 0 landed
    __builtin_amdgcn_s_barrier();
    READFRAGS(0, aR[0], bR[0]);

    #define BODY(kt, CB, NB, VMW) do {                                       \
        STAGE((kt) + 3, ((kt) + 3) & 3);                                     \
        asm volatile("s_waitcnt " VMW " lgkmcnt(0)" ::: "memory");           \
        __builtin_amdgcn_s_barrier();                                        \
        READFRAGS(((kt) + 1) & 3, aR[NB], bR[NB]);                           \
        MFMA16(aR[CB], bR[CB]);                                              \
    } while (0)

    // main: kt = 0..139 (70 unrolled pairs); kt+3 <= 142 < NT always.
    for (int k2 = 0; k2 < 70; ++k2) {
        const int kt = k2 * 2;
        BODY(kt,     0, 1, "vmcnt(8)");
        BODY(kt + 1, 1, 0, "vmcnt(8)");
    }
    // tail: kt = 140..143 peeled
    STAGE(143, 3);
    asm volatile("s_waitcnt vmcnt(8) lgkmcnt(0)" ::: "memory");  // tile 141
    __builtin_amdgcn_s_barrier();
    READFRAGS(1, aR[1], bR[1]);
    MFMA16(aR[0], bR[0]);                                        // tile 140

    asm volatile("s_waitcnt vmcnt(4) lgkmcnt(0)" ::: "memory");  // tile 142
    __builtin_amdgcn_s_barrier();
    READFRAGS(2, aR[0], bR[0]);
    MFMA16(aR[1], bR[1]);                                        // tile 141

    asm volatile("s_waitcnt vmcnt(0) lgkmcnt(0)" ::: "memory");  // tile 143
    __builtin_amdgcn_s_barrier();
    READFRAGS(3, aR[1], bR[1]);
    MFMA16(aR[0], bR[0]);                                        // tile 142

    MFMA16(aR[1], bR[1]);                                        // tile 143

    // ---- wave-pair K reduction via LDS, then C store (kp=0 waves) ----------
    __syncthreads();                       // drains all counters; repurpose Sm
    const int pairw = wave & 3;
    if (kp == 1) {
        #pragma unroll
        for (int m = 0; m < 4; ++m)
            #pragma unroll
            for (int n = 0; n < 4; ++n)
                *(f32x4*)(Sm + pairw * 16384 + (m * 4 + n) * 1024 + lane * 16)
                    = acc[m][n];
    }
    __syncthreads();
    if (kp == 0) {
        #pragma unroll
        for (int m = 0; m < 4; ++m) {
            const int row = m0 + wr * 64 + m * 16 + kgrp * 4;
            #pragma unroll
            for (int n = 0; n < 4; ++n) {
                f32x4 t = *(const f32x4*)(Sm + pairw * 16384 + (m * 4 + n) * 1024 + lane * 16);
                f32x4 s = acc[m][n] + t;
                const int col = n0 + wn * 64 + n * 16 + frow;
                float* cp = C + (size_t)row * OUT_F + col;
                #pragma unroll
                for (int r = 0; r < 4; ++r)
                    cp[(size_t)r * OUT_F] = s[r];
            }
        }
    }
    #undef STAGE
    #undef READFRAGS
    #undef MFMA16
    #undef BODY
}

// ---------------------------------------------------------------------------
extern "C" void kernel_launch(void* const* d_in, const int* in_sizes, int n_in,
                              void* d_out, int out_size, void* d_ws, size_t ws_size,
                              hipStream_t stream) {
    const float* x        = (const float*)d_in[0];
    const float* base_w   = (const float*)d_in[1];
    const float* spline_w = (const float*)d_in[2];
    const float* scaler   = (const float*)d_in[3];
    float* out = (float*)d_out;

    const size_t act_bytes = (size_t)BATCH * KTOT * 2;   // 75.5 MB
    const size_t w_bytes   = (size_t)OUT_F * KTOT * 2;   // 18.9 MB
    if (ws_size < act_bytes + w_bytes) return;

    unsigned short* Act = (unsigned short*)d_ws;
    unsigned short* Wb  = (unsigned short*)((char*)d_ws + act_bytes);

    build_w_kernel<<<(OUT_F * IN_F) / 256, 256, 0, stream>>>(base_w, spline_w, scaler, Wb);
    build_act_kernel<<<(BATCH * IN_F) / 256, 256, 0, stream>>>(x, Act);
    gemm_kernel<<<(BATCH / BM) * (OUT_F / BN), 512, 0, stream>>>(Act, Wb, out);
}

// Round 6
// 109.074 us; speedup vs baseline: 1.1480x; 1.1480x over previous
//
#include <hip/hip_runtime.h>
#include <hip/hip_bf16.h>
#include <cstdint>

#define IN_F   1024
#define OUT_F  1024
#define KTOT   (IN_F + IN_F * 8)      // 9216
#define BATCH  4096

#define BM 128
#define BN 128
#define BK 64
#define NT (KTOT / BK)                // 144 K-steps
#define ROWB (BK * 2)                 // 128 bytes per LDS row
#define SLOT_B 32768                  // bytes per ring slot (A 16K | B 16K)

typedef __attribute__((ext_vector_type(8))) __bf16 bf16x8;
typedef __attribute__((ext_vector_type(4))) float  f32x4;
typedef __attribute__((ext_vector_type(8))) short  short8v;

typedef __attribute__((address_space(1))) const uint32_t gu32;
typedef __attribute__((address_space(3))) uint32_t       lu32;

__device__ __forceinline__ void gl_lds16(const void* g, void* l) {
    __builtin_amdgcn_global_load_lds((gu32*)g, (lu32*)l, 16, 0, 0);
}

// float -> bf16 RNE
__device__ __forceinline__ unsigned short f2bf(float f) {
    unsigned int u = __builtin_bit_cast(unsigned int, f);
    return (unsigned short)((u + 0x7fffu + ((u >> 16) & 1u)) >> 16);
}

__device__ __forceinline__ float knot(int i) { return 0.4f * (float)i - 2.2f; }

// ---------------------------------------------------------------------------
// Merged prep: blocks [0,16384) build Act (BATCH x KTOT), blocks [16384,20480)
// build Wb (OUT_F x KTOT). One launch instead of two (saves a stream gap;
// both parts are HBM-BW-bound and tile the machine together).
// ---------------------------------------------------------------------------
__global__ void build_all_kernel(const float* __restrict__ x,
                                 const float* __restrict__ base_w,
                                 const float* __restrict__ spline_w,
                                 const float* __restrict__ scaler,
                                 unsigned short* __restrict__ Act,
                                 unsigned short* __restrict__ Wb) {
    const int bid = blockIdx.x;
    if (bid < 16384) {
        // ---- build Act: [silu(x) | basis(x)] ----
        int idx = bid * 256 + threadIdx.x;        // 0 .. 4096*1024-1
        int b = idx >> 10;
        int j = idx & 1023;

        float xv = x[idx];
        float sil = xv * __frcp_rn(1.0f + __expf(-xv));
        Act[(size_t)b * KTOT + j] = f2bf(sil);

        const float r1 = 1.0f / (0.4f + 1e-8f);
        const float r2 = 1.0f / (0.8f + 1e-8f);
        const float r3 = 1.0f / (1.2f + 1e-8f);

        float bas[11];
        #pragma unroll
        for (int i = 0; i < 11; ++i)
            bas[i] = (xv >= knot(i) && xv < knot(i + 1)) ? 1.0f : 0.0f;
        #pragma unroll
        for (int i = 0; i < 10; ++i)
            bas[i] = (xv - knot(i)) * r1 * bas[i] + (knot(i + 2) - xv) * r1 * bas[i + 1];
        #pragma unroll
        for (int i = 0; i < 9; ++i)
            bas[i] = (xv - knot(i)) * r2 * bas[i] + (knot(i + 3) - xv) * r2 * bas[i + 1];
        #pragma unroll
        for (int i = 0; i < 8; ++i)
            bas[i] = (xv - knot(i)) * r3 * bas[i] + (knot(i + 4) - xv) * r3 * bas[i + 1];

        short8v v;
        #pragma unroll
        for (int c = 0; c < 8; ++c) v[c] = (short)f2bf(bas[c]);
        *(short8v*)(Act + (size_t)b * KTOT + IN_F + (size_t)j * 8) = v;
    } else {
        // ---- build Wb: [base_w | spline_w * scaler] ----
        int idx = (bid - 16384) * 256 + threadIdx.x;  // 0 .. 1024*1024-1
        int o = idx >> 10;
        int j = idx & 1023;

        Wb[(size_t)o * KTOT + j] = f2bf(base_w[idx]);

        float s = scaler[idx];
        const float4* sw4 = (const float4*)(spline_w + (size_t)idx * 8);
        float4 w0 = sw4[0], w1 = sw4[1];

        short8v v;
        v[0] = (short)f2bf(w0.x * s); v[1] = (short)f2bf(w0.y * s);
        v[2] = (short)f2bf(w0.z * s); v[3] = (short)f2bf(w0.w * s);
        v[4] = (short)f2bf(w1.x * s); v[5] = (short)f2bf(w1.y * s);
        v[6] = (short)f2bf(w1.z * s); v[7] = (short)f2bf(w1.w * s);
        *(short8v*)(Wb + (size_t)o * KTOT + IN_F + (size_t)j * 8) = v;
    }
}

// ---------------------------------------------------------------------------
// GEMM: C (4096x1024) f32 = Act . Wb^T.  128x128 tile, BK=64.
// Structure identical to r5 (reg fragment double-buffer, ring-4 LDS, depth-3
// staging, counted vmcnt, setprio around MFMA).
// NEW (r6): XCD-partitioned block mapping. bid%8 = XCD. Each XCD owns a
// contiguous M-range (4 A-panels) and sweeps ALL nblks:
//   mblk = (bid&7)*4 + ((bid>>3)&3), nblk = bid>>5.
// A panel is then read by exactly ONE XCD (L2-resident after first touch);
// B streams once per XCD (128KB/step, L2-held). L3->L2 traffic drops
// ~740MB -> ~230MB per GEMM. r5's mapping scattered A (the 4x bigger
// operand) across all 8 XCD L2s -> fabric-BW bound (~8.4 TB/s observed).
// ---------------------------------------------------------------------------
__global__ __launch_bounds__(512)
void gemm_kernel(const unsigned short* __restrict__ Act,
                 const unsigned short* __restrict__ Wb,
                 float* __restrict__ C) {
    __shared__ char Sm[4 * SLOT_B];    // 128 KB ring; reused for reduction

    const int tid  = threadIdx.x;
    const int lane = tid & 63;
    const int wave = tid >> 6;        // 0..7
    const int kp   = wave >> 2;       // K-parity 0/1
    const int wr   = (wave >> 1) & 1; // M half
    const int wn   = wave & 1;        // N half

    const int bid  = blockIdx.x;
    const int xcd  = bid & 7;
    const int loc  = bid >> 3;               // 0..31
    const int mblk = xcd * 4 + (loc & 3);    // 4 M-panels per XCD
    const int nblk = loc >> 2;               // all 8 N-panels per XCD
    const int m0 = mblk * BM;
    const int n0 = nblk * BN;

    const int frow = lane & 15;
    const int kgrp = lane >> 4;       // 0..3

    f32x4 acc[4][4] = {};             // 64 VGPRs: 64x64 per wave

    // staging map: thread t covers 16 B at tile byte offset o (shot0) / o+8192
    const int o    = tid * 16;                 // 0..8191
    const int row0 = o >> 7;                   // 0..63
    const int colb = o & 127;
    const int scol = colb ^ ((row0 & 7) << 4); // pre-swizzled source column

    const char* aS0 = (const char*)Act + (size_t)(m0 + row0) * (KTOT * 2) + scol;
    const char* aS1 = aS0 + (size_t)64 * (KTOT * 2);
    const char* bS0 = (const char*)Wb  + (size_t)(n0 + row0) * (KTOT * 2) + scol;
    const char* bS1 = bS0 + (size_t)64 * (KTOT * 2);

    #define STAGE(kt, sl) do {                                       \
        const size_t kk = (size_t)(kt) * ROWB;                       \
        char* d = Sm + (size_t)(sl) * SLOT_B + o;                    \
        gl_lds16(aS0 + kk, d);                                       \
        gl_lds16(aS1 + kk, d + 8192);                                \
        gl_lds16(bS0 + kk, d + 16384);                               \
        gl_lds16(bS1 + kk, d + 24576);                               \
    } while (0)

    const int swz = (lane & 7) << 4;           // fragment row&7 == lane&7
    const int kb  = kp * 64 + kgrp * 16;       // this wave's K=32 half-slice

    bf16x8 aR[2][4], bR[2][4];                 // fragment double-buffer

    #define READFRAGS(sl, AB, BB) do {                                       \
        const char* base_ = Sm + (size_t)(sl) * SLOT_B;                      \
        _Pragma("unroll")                                                    \
        for (int m = 0; m < 4; ++m) {                                        \
            const int r = wr * 64 + m * 16 + frow;                           \
            (AB)[m] = *(const bf16x8*)(base_ + r * ROWB + (kb ^ swz));       \
        }                                                                    \
        _Pragma("unroll")                                                    \
        for (int n = 0; n < 4; ++n) {                                        \
            const int r = wn * 64 + n * 16 + frow;                           \
            (BB)[n] = *(const bf16x8*)(base_ + 16384 + r * ROWB + (kb ^ swz)); \
        }                                                                    \
    } while (0)

    #define MFMA16(AB, BB) do {                                              \
        __builtin_amdgcn_s_setprio(1);                                       \
        _Pragma("unroll")                                                    \
        for (int m = 0; m < 4; ++m)                                          \
            _Pragma("unroll")                                                \
            for (int n = 0; n < 4; ++n)                                      \
                acc[m][n] = __builtin_amdgcn_mfma_f32_16x16x32_bf16(         \
                                (AB)[m], (BB)[n], acc[m][n], 0, 0, 0);       \
        __builtin_amdgcn_s_setprio(0);                                       \
    } while (0)

    // ---- prologue: stage 3 tiles, land tile 0, preload its fragments ------
    STAGE(0, 0);
    STAGE(1, 1);
    STAGE(2, 2);
    asm volatile("s_waitcnt vmcnt(8)" ::: "memory");   // tile 0 landed
    __builtin_amdgcn_s_barrier();
    READFRAGS(0, aR[0], bR[0]);

    #define BODY(kt, CB, NB, VMW) do {                                       \
        STAGE((kt) + 3, ((kt) + 3) & 3);                                     \
        asm volatile("s_waitcnt " VMW " lgkmcnt(0)" ::: "memory");           \
        __builtin_amdgcn_s_barrier();                                        \
        READFRAGS(((kt) + 1) & 3, aR[NB], bR[NB]);                           \
        MFMA16(aR[CB], bR[CB]);                                              \
    } while (0)

    // main: kt = 0..139 (70 unrolled pairs); kt+3 <= 142 < NT always.
    for (int k2 = 0; k2 < 70; ++k2) {
        const int kt = k2 * 2;
        BODY(kt,     0, 1, "vmcnt(8)");
        BODY(kt + 1, 1, 0, "vmcnt(8)");
    }
    // tail: kt = 140..143 peeled
    STAGE(143, 3);
    asm volatile("s_waitcnt vmcnt(8) lgkmcnt(0)" ::: "memory");  // tile 141
    __builtin_amdgcn_s_barrier();
    READFRAGS(1, aR[1], bR[1]);
    MFMA16(aR[0], bR[0]);                                        // tile 140

    asm volatile("s_waitcnt vmcnt(4) lgkmcnt(0)" ::: "memory");  // tile 142
    __builtin_amdgcn_s_barrier();
    READFRAGS(2, aR[0], bR[0]);
    MFMA16(aR[1], bR[1]);                                        // tile 141

    asm volatile("s_waitcnt vmcnt(0) lgkmcnt(0)" ::: "memory");  // tile 143
    __builtin_amdgcn_s_barrier();
    READFRAGS(3, aR[1], bR[1]);
    MFMA16(aR[0], bR[0]);                                        // tile 142

    MFMA16(aR[1], bR[1]);                                        // tile 143

    // ---- wave-pair K reduction via LDS, then C store (kp=0 waves) ----------
    __syncthreads();                       // drains all counters; repurpose Sm
    const int pairw = wave & 3;
    if (kp == 1) {
        #pragma unroll
        for (int m = 0; m < 4; ++m)
            #pragma unroll
            for (int n = 0; n < 4; ++n)
                *(f32x4*)(Sm + pairw * 16384 + (m * 4 + n) * 1024 + lane * 16)
                    = acc[m][n];
    }
    __syncthreads();
    if (kp == 0) {
        #pragma unroll
        for (int m = 0; m < 4; ++m) {
            const int row = m0 + wr * 64 + m * 16 + kgrp * 4;
            #pragma unroll
            for (int n = 0; n < 4; ++n) {
                f32x4 t = *(const f32x4*)(Sm + pairw * 16384 + (m * 4 + n) * 1024 + lane * 16);
                f32x4 s = acc[m][n] + t;
                const int col = n0 + wn * 64 + n * 16 + frow;
                float* cp = C + (size_t)row * OUT_F + col;
                #pragma unroll
                for (int r = 0; r < 4; ++r)
                    cp[(size_t)r * OUT_F] = s[r];
            }
        }
    }
    #undef STAGE
    #undef READFRAGS
    #undef MFMA16
    #undef BODY
}

// ---------------------------------------------------------------------------
extern "C" void kernel_launch(void* const* d_in, const int* in_sizes, int n_in,
                              void* d_out, int out_size, void* d_ws, size_t ws_size,
                              hipStream_t stream) {
    const float* x        = (const float*)d_in[0];
    const float* base_w   = (const float*)d_in[1];
    const float* spline_w = (const float*)d_in[2];
    const float* scaler   = (const float*)d_in[3];
    float* out = (float*)d_out;

    const size_t act_bytes = (size_t)BATCH * KTOT * 2;   // 75.5 MB
    const size_t w_bytes   = (size_t)OUT_F * KTOT * 2;   // 18.9 MB
    if (ws_size < act_bytes + w_bytes) return;

    unsigned short* Act = (unsigned short*)d_ws;
    unsigned short* Wb  = (unsigned short*)((char*)d_ws + act_bytes);

    build_all_kernel<<<16384 + 4096, 256, 0, stream>>>(x, base_w, spline_w, scaler, Act, Wb);
    gemm_kernel<<<(BATCH / BM) * (OUT_F / BN), 512, 0, stream>>>(Act, Wb, out);
}